// Round 10
// baseline (285.571 us; speedup 1.0000x reference)
//
#include <hip/hip_runtime.h>
#include <hip/hip_bf16.h>

// GraphSAGE 3-layer: 40 -> 64 -> 128 -> 3, mean aggregation over fixed edges.
// R23 (on R22): degree-balanced gather. R18-R22 nulls (depth/grid/order/pad/
// occupancy) point at intra-block imbalance: slot-per-node gather waits on the
// block's MAX degree (~29) vs mean 16 -> ~1.8x inflation at the barrier.
//  - Slots now process equal shares of the block's FLAT edge list; per-node
//    partials flushed to fp32 LDS accumulators (ds_add_f32, ~2-3 flushes/slot).
//  - Every slot does ceil(len/16) edges regardless of degree distribution.
//  - deg derived from staged local row offsets (global deg_inv load dropped).

static constexpr int NN = 100000;
static constexpr int EE = 1600000;
static constexpr int NRANGE = 256;
static constexpr int RSIZE = (NN + NRANGE - 1) / NRANGE;   // 391
static constexpr int RPAD = 512;                           // pow2 >= RSIZE
static constexpr int NBUCKET = 8 * NRANGE;                 // 2048
static constexpr int CAP = 1024;     // per-bucket capacity (mean ~781, +8.7 sigma)
static constexpr int BCHUNK = 2048;  // edges per block (8 per thread)
static constexpr int BUCKET_BLOCKS = (EE + BCHUNK - 1) / BCHUNK;  // 782
static constexpr int CVT_BLOCKS = (NN * 8 + 255) / 256;           // 3125 (padded rows)
static constexpr int NCHUNK16 = NN / 16;                          // 6250 exact
static constexpr int EIDX = 512;     // staged indices per 16-node chunk (mean 256, +16 sigma)

// packed weight-frag layout (shorts): W1 frags | W2 frags | W4 frags
static constexpr int W1OFF = 0;                 // 4 tiles * 4 ks * 64 lanes * 8
static constexpr int W2OFF = 4 * 4 * 64 * 8;    // 8192
static constexpr int W4OFF = W2OFF + 8 * 4 * 64 * 8;  // 24576
static constexpr int WPACK_SHORTS = W4OFF + 4 * 64 * 8;  // 26624
static constexpr int PACK_ITEMS = 4 * 4 * 64 + 8 * 4 * 64 + 4 * 64;  // 3328
static constexpr int PACK_BLOCKS = (PACK_ITEMS + 255) / 256;         // 13

typedef __attribute__((ext_vector_type(8))) short short8;
typedef __attribute__((ext_vector_type(4))) float f32x4;

__device__ __forceinline__ float bf2f(unsigned short u) {
    union { unsigned int i; float f; } c; c.i = ((unsigned int)u) << 16; return c.f;
}
__device__ __forceinline__ unsigned short f2bf(float f) {
    union { float f; unsigned int i; } c; c.f = f;
    unsigned int x = c.i;
    return (unsigned short)((x + 0x7fffu + ((x >> 16) & 1u)) >> 16);   // RNE
}

// ---------------- phase 1 (fused): bucket edges + x->bf16 convert(padded) + weight pack ----------------
__global__ __launch_bounds__(256) void k_bucket_cvt(const int* __restrict__ src, const int* __restrict__ dst,
                                                    int* __restrict__ pcur, unsigned int* __restrict__ pairs,
                                                    const float* __restrict__ x, unsigned short* __restrict__ xb,
                                                    const float* __restrict__ W1l, const float* __restrict__ W1r,
                                                    const float* __restrict__ W2l, const float* __restrict__ W2r,
                                                    const float* __restrict__ W4l, const float* __restrict__ W4r,
                                                    unsigned short* __restrict__ wpack) {
    __shared__ int cnt[NRANGE];
    __shared__ int base[NRANGE];
    const int tid = threadIdx.x;
    if (blockIdx.x >= BUCKET_BLOCKS + CVT_BLOCKS) {
        // ---- weight-pack branch: frag layout (t*KS+ks)*64+lane -> short8 ----
        int idx = (blockIdx.x - BUCKET_BLOCKS - CVT_BLOCKS) * 256 + tid;
        if (idx < PACK_ITEMS) {
            short8 v;
            if (idx < 1024) {                       // W1: Fin=40, 4 tiles
                int l = idx & 63, ks = (idx >> 6) & 3, t = idx >> 8;
                int o = t * 16 + (l & 15);
                int kbase = ks * 32 + (l >> 4) * 8;
#pragma unroll
                for (int j = 0; j < 8; ++j) {
                    int k = kbase + j; float w;
                    if (k < 64) w = (k < 40) ? W1l[o * 40 + k] : 0.f;
                    else { int k2 = k - 64; w = (k2 < 40) ? W1r[o * 40 + k2] : 0.f; }
                    v[j] = (short)f2bf(w);
                }
                *(short8*)&wpack[W1OFF + idx * 8] = v;
            } else if (idx < 3072) {                // W2: Fin=64, 8 tiles
                int i2 = idx - 1024;
                int l = i2 & 63, ks = (i2 >> 6) & 3, t = i2 >> 8;
                int o = t * 16 + (l & 15);
                int kbase = ks * 32 + (l >> 4) * 8;
#pragma unroll
                for (int j = 0; j < 8; ++j) {
                    int k = kbase + j;
                    float w = (k < 64) ? W2l[o * 64 + k] : W2r[o * 64 + (k - 64)];
                    v[j] = (short)f2bf(w);
                }
                *(short8*)&wpack[W2OFF + i2 * 8] = v;
            } else {                                // W4: [z|r] narrow, K=128
                int i4 = idx - 3072;
                int l = i4 & 63, ks = i4 >> 6;
                int o = l & 15;
                int kbase = ks * 32 + (l >> 4) * 8;
#pragma unroll
                for (int j = 0; j < 8; ++j) {
                    int k = kbase + j;
                    float w = 0.f;
                    if (o < 3) w = W4l[o * 128 + k];
                    else if (o >= 4 && o < 7) w = W4r[(o - 4) * 128 + k];
                    v[j] = (short)f2bf(w);
                }
                *(short8*)&wpack[W4OFF + i4 * 8] = v;
            }
        }
        return;
    }
    if (blockIdx.x >= BUCKET_BLOCKS) {
        // ---- convert branch: fp32 -> bf16, rows PADDED 40 -> 64 shorts ----
        int i = (blockIdx.x - BUCKET_BLOCKS) * 256 + tid;     // 8-short chunk id
        if (i < NN * 8) {
            int node = i >> 3, c = i & 7;
            short8 v = {0, 0, 0, 0, 0, 0, 0, 0};
            if (c < 5) {
                const float4* p = (const float4*)(x + (size_t)node * 40 + c * 8);
                float4 a = p[0], b = p[1];
                v[0] = (short)f2bf(a.x); v[1] = (short)f2bf(a.y); v[2] = (short)f2bf(a.z); v[3] = (short)f2bf(a.w);
                v[4] = (short)f2bf(b.x); v[5] = (short)f2bf(b.y); v[6] = (short)f2bf(b.z); v[7] = (short)f2bf(b.w);
            }
            *(short8*)(xb + (size_t)i * 8) = v;
        }
        return;
    }
    // ---- bucket branch: block-local reservation, packed (s | dloc<<17) ----
    const int part = blockIdx.x & 7;            // this block's XCD tag (round-robin)
    const int e0 = blockIdx.x * BCHUNK;
    cnt[tid] = 0;                               // NRANGE == blockDim == 256
    __syncthreads();
    int r_[8], lp_[8];
    unsigned int p_[8];
#pragma unroll
    for (int j = 0; j < 8; ++j) {
        int e = e0 + j * 256 + tid;
        r_[j] = -1;
        if (e < EE) {
            int d = dst[e];
            int s = src[e];
            int r = d / RSIZE;                  // const-divide -> magic mul
            r_[j] = r;
            p_[j] = (unsigned int)s | ((unsigned int)(d - r * RSIZE) << 17);
            lp_[j] = atomicAdd(&cnt[r], 1);     // fast LDS atomic
        }
    }
    __syncthreads();
    {
        int c = cnt[tid];
        base[tid] = (c > 0) ? atomicAdd(&pcur[(part << 8) | tid], c) : 0;  // 1 global RMW / bucket / block
    }
    __syncthreads();
#pragma unroll
    for (int j = 0; j < 8; ++j) {
        if (r_[j] >= 0) {
            int pos = base[r_[j]] + lp_[j];
            if (pos < CAP) pairs[(size_t)((part << 8) | r_[j]) * CAP + pos] = p_[j];
        }
    }
}

// ---------------- fused CSR build: degree count + scan + row_start/deg_inv + scatter ----------------
__global__ __launch_bounds__(1024) void k_build(const unsigned int* __restrict__ pairs,
                                                const int* __restrict__ pcur,
                                                int* __restrict__ row_start, float* __restrict__ deg_inv,
                                                int* __restrict__ csr_src) {
    __shared__ int ldeg[RPAD];
    __shared__ int lrs[RPAD];
    __shared__ int rtot[NRANGE];
    const int tid = threadIdx.x;
    const int r = blockIdx.x;
    const int lo = r * RSIZE;
    const int nloc = (lo + RSIZE <= NN) ? RSIZE : (NN - lo);
    for (int t = tid; t < RPAD; t += 1024) ldeg[t] = 0;
    __syncthreads();
    // pass 1: degree histogram
    for (int p = 0; p < 8; ++p) {
        int b = (p << 8) | r;
        int len = pcur[b]; if (len > CAP) len = CAP;
        const unsigned int* bp = pairs + (size_t)b * CAP;
        for (int i = tid; i < len; i += 1024)
            atomicAdd(&ldeg[bp[i] >> 17], 1);
    }
    // per-range totals from pcur (independent of ldeg)
    if (tid < NRANGE) {
        int s = 0;
#pragma unroll
        for (int p = 0; p < 8; ++p) {
            int c = pcur[(p << 8) | tid];
            s += (c > CAP) ? CAP : c;
        }
        rtot[tid] = s;
    }
    __syncthreads();
    // inclusive scan of rtot (256 values)
    for (int d = 1; d < NRANGE; d <<= 1) {
        int t = (tid < NRANGE && tid >= d) ? rtot[tid - d] : 0;
        __syncthreads();
        if (tid < NRANGE) rtot[tid] += t;
        __syncthreads();
    }
    const int rbase = (r == 0) ? 0 : rtot[r - 1];
    // inclusive scan of ldeg -> lrs (512 values)
    if (tid < RPAD) lrs[tid] = ldeg[tid];
    __syncthreads();
    for (int d = 1; d < RPAD; d <<= 1) {
        int t = (tid < RPAD && tid >= d) ? lrs[tid - d] : 0;
        __syncthreads();
        if (tid < RPAD) lrs[tid] += t;
        __syncthreads();
    }
    // write row_start / deg_inv; convert lrs to exclusive, reset ldeg to cursors
    int excl = 0, dg = 0;
    if (tid < RPAD) { dg = ldeg[tid]; excl = lrs[tid] - dg; }
    if (tid < nloc) {
        row_start[lo + tid] = rbase + excl;
        deg_inv[lo + tid] = (dg > 0) ? 1.0f / (float)dg : 0.0f;
    }
    if (r == 0 && tid == 0) row_start[NN] = EE;
    __syncthreads();
    if (tid < RPAD) { lrs[tid] = excl; ldeg[tid] = 0; }
    __syncthreads();
    // pass 2: scatter
    for (int p = 0; p < 8; ++p) {
        int b = (p << 8) | r;
        int len = pcur[b]; if (len > CAP) len = CAP;
        const unsigned int* bp = pairs + (size_t)b * CAP;
        for (int i = tid; i < len; i += 1024) {
            unsigned int pk = bp[i];
            int dloc = pk >> 17;
            int lp = atomicAdd(&ldeg[dloc], 1);             // LDS cursor
            csr_src[rbase + lrs[dloc] + lp] = (int)(pk & 0x1FFFFu);
        }
    }
}

// ---------------- fused layer: BALANCED gather-mean (LDS) + MFMA GEMM [+ zr epilogue] ----------------
// One 16-node chunk per 128-thread block (grid = 6250). Slot w processes edges
// [(w*len)/16, ((w+1)*len)/16) of the block's flat edge list; per-node partials
// flushed to fp32 LDS accumulators (ds_add_f32). Feature rows stride-64 shorts.
template<int Fout, bool RELU, bool ZR, int WOFF>
__global__ __launch_bounds__(128, 8) void k_fused(const unsigned short* __restrict__ xin,
                                                  const int* __restrict__ row_start,
                                                  const int* __restrict__ csr_src,
                                                  const unsigned short* __restrict__ wpack,
                                                  const float* __restrict__ bias,
                                                  unsigned short* __restrict__ out,
                                                  float* __restrict__ z,
                                                  float* __restrict__ rr_) {
    constexpr int KS = 4;
    constexpr int TILES = Fout / 16;
    constexpr int TPW = TILES / 2;              // tiles per wave (2 waves)
    constexpr int SMEAN = 0;                    // [16][72]
    constexpr int SROOT = 16 * 72;              // [16][72]
    constexpr int SH2 = 2 * 16 * 72;            // [16][136] (ZR only)
    constexpr int SHM = 2 * 16 * 72 + (ZR ? 16 * 136 : 0);
    __shared__ short shm[SHM];
    __shared__ float facc[16][64];              // fp32 per-node accumulators (4KB)
    __shared__ int lidx[EIDX];
    __shared__ int rsl[17];                     // local row starts
    const int tid = threadIdx.x;
    const int lane = tid & 63;
    const int wv = tid >> 6;                    // 0..1
    const int nbase = blockIdx.x * 16;

    float bias_t[TPW];
#pragma unroll
    for (int tt = 0; tt < TPW; ++tt) bias_t[tt] = bias[(wv * TPW + tt) * 16 + (lane & 15)];

    // ---- phase A0: stage edge indices + local row offsets; zero facc ----
    const int rs_blk = row_start[nbase];
    if (tid < 17) rsl[tid] = row_start[nbase + tid] - rs_blk;
    {
        float4* fz = (float4*)facc;
        fz[tid * 2] = (float4){0.f, 0.f, 0.f, 0.f};
        fz[tid * 2 + 1] = (float4){0.f, 0.f, 0.f, 0.f};
    }
    const int nedge = row_start[nbase + 16] - rs_blk;
    for (int i = tid; i < nedge && i < EIDX; i += 128) lidx[i] = csr_src[rs_blk + i];
    __syncthreads();

    const int w8 = tid >> 3;                    // slot 0..15
    const int c = tid & 7;

    // ---- phase A: balanced gather (each slot = len/16 edges) ----
    {
        const int len = rsl[16];
        const int g0 = (w8 * len) >> 4;
        const int g1 = ((w8 + 1) * len) >> 4;
        if (g0 < g1) {
            const unsigned short* xq = xin + c * 8;
            int node = 0;
            while (rsl[node + 1] <= g0) ++node;
            int cur_end = rsl[node + 1];
            float acc[8] = {0, 0, 0, 0, 0, 0, 0, 0};
            int g = g0;
            while (g < g1) {
                const int take = (g1 - g < 4) ? (g1 - g) : 4;
                short8 v[4];
#pragma unroll
                for (int j = 0; j < 4; ++j) {
                    int gi = (j < take) ? (g + j) : (g1 - 1);
                    int s = (gi < EIDX) ? lidx[gi] : csr_src[rs_blk + gi];
                    v[j] = *(const short8*)(xq + (size_t)s * 64);
                }
#pragma unroll
                for (int j = 0; j < 4; ++j) {
                    if (j < take) {
                        while (g + j >= cur_end) {          // flush & advance (handles empty nodes)
#pragma unroll
                            for (int t = 0; t < 8; ++t) { atomicAdd(&facc[node][c * 8 + t], acc[t]); acc[t] = 0.f; }
                            ++node; cur_end = rsl[node + 1];
                        }
#pragma unroll
                        for (int t = 0; t < 8; ++t) acc[t] += bf2f((unsigned short)v[j][t]);
                    }
                }
                g += 4;
            }
#pragma unroll
            for (int t = 0; t < 8; ++t) atomicAdd(&facc[node][c * 8 + t], acc[t]);
        }
    }
    __syncthreads();
    // ---- finalize mean + stage root (thread = (node w8, chunk c)) ----
    {
        const int dg = rsl[w8 + 1] - rsl[w8];
        const float di = (dg > 0) ? 1.0f / (float)dg : 0.0f;
        short8 mv;
#pragma unroll
        for (int t = 0; t < 8; ++t) mv[t] = (short)f2bf(facc[w8][c * 8 + t] * di);
        short8 rv = *(const short8*)(xin + (size_t)(nbase + w8) * 64 + c * 8);
        *(short8*)&shm[SMEAN + w8 * 72 + c * 8] = mv;
        *(short8*)&shm[SROOT + w8 * 72 + c * 8] = rv;
    }
    __syncthreads();
    // ---- phase B: MFMA. A-frags from LDS once; B-frags streamed from wpack ----
    short8 af[KS];
#pragma unroll
    for (int ks = 0; ks < KS; ++ks) {
        const int base = (ks < 2) ? SMEAN : SROOT;
        const int g = (ks & 1) * 4 + (lane >> 4);
        af[ks] = *(const short8*)&shm[base + (lane & 15) * 72 + g * 8];
    }
    f32x4 acc2[TPW];
#pragma unroll
    for (int tt = 0; tt < TPW; ++tt) acc2[tt] = (f32x4){0.f, 0.f, 0.f, 0.f};
#pragma unroll
    for (int tt = 0; tt < TPW; ++tt) {
        short8 bt[KS];
#pragma unroll
        for (int ks = 0; ks < KS; ++ks)
            bt[ks] = *(const short8*)&wpack[WOFF + (((wv * TPW + tt) * KS + ks) * 64 + lane) * 8];
#pragma unroll
        for (int ks = 0; ks < KS; ++ks)
            acc2[tt] = __builtin_amdgcn_mfma_f32_16x16x32_bf16(af[ks], bt[ks], acc2[tt], 0, 0, 0);
    }
    if constexpr (!ZR) {
        const int nrow = nbase + (lane >> 4) * 4;
#pragma unroll
        for (int tt = 0; tt < TPW; ++tt) {
            int col = (wv * TPW + tt) * 16 + (lane & 15);
#pragma unroll
            for (int q = 0; q < 4; ++q) {
                float v = acc2[tt][q] + bias_t[tt];
                if (RELU) v = fmaxf(v, 0.f);
                out[(size_t)(nrow + q) * Fout + col] = f2bf(v);
            }
        }
    } else {
        // relu'd h2 tile -> LDS
        const int row0 = (lane >> 4) * 4;
#pragma unroll
        for (int tt = 0; tt < TPW; ++tt) {
            int col = (wv * TPW + tt) * 16 + (lane & 15);
#pragma unroll
            for (int q = 0; q < 4; ++q) {
                float v = acc2[tt][q] + bias_t[tt];
                if (RELU) v = fmaxf(v, 0.f);
                shm[SH2 + (row0 + q) * 136 + col] = (short)f2bf(v);
            }
        }
        __syncthreads();
        if (wv == 0) {
            short8 b4r[4];
#pragma unroll
            for (int ks = 0; ks < 4; ++ks)
                b4r[ks] = *(const short8*)&wpack[W4OFF + (ks * 64 + lane) * 8];
            const int row = lane & 15;
            f32x4 az = (f32x4){0.f, 0.f, 0.f, 0.f};
#pragma unroll
            for (int ks = 0; ks < 4; ++ks) {
                short8 a4 = *(const short8*)&shm[SH2 + row * 136 + (ks * 4 + (lane >> 4)) * 8];
                az = __builtin_amdgcn_mfma_f32_16x16x32_bf16(a4, b4r[ks], az, 0, 0, 0);
            }
            const int col = lane & 15;
            const int nr = nbase + (lane >> 4) * 4;
            if (col < 3) {
#pragma unroll
                for (int q = 0; q < 4; ++q) z[(size_t)(nr + q) * 4 + col] = az[q];
            } else if (col >= 4 && col < 7) {
#pragma unroll
                for (int q = 0; q < 4; ++q) rr_[(size_t)(nr + q) * 4 + col - 4] = az[q];
            }
        }
    }
}

// ---------------- final: out = mean(z)[n] + r[n] + b4 (rows 8-deep) ----------------
__global__ __launch_bounds__(256) void k_final(const float* __restrict__ z, const float* __restrict__ r,
                                               const float* __restrict__ b4,
                                               const int* __restrict__ row_start, const int* __restrict__ csr_src,
                                               const float* __restrict__ deg_inv, float* __restrict__ out) {
    int n = blockIdx.x * 256 + threadIdx.x;
    if (n >= NN) return;
    const int rs = row_start[n], re = row_start[n + 1];
    float a0 = 0, a1 = 0, a2 = 0, b0 = 0, b1 = 0, b2 = 0;
    const float4* z4 = (const float4*)z;
    int k = rs;
    for (; k + 8 <= re; k += 8) {
        int e[8];
#pragma unroll
        for (int j = 0; j < 8; ++j) e[j] = csr_src[k + j];
        float4 v[8];
#pragma unroll
        for (int j = 0; j < 8; ++j) v[j] = z4[e[j]];
#pragma unroll
        for (int j = 0; j < 8; j += 2) {
            a0 += v[j].x; a1 += v[j].y; a2 += v[j].z;
            b0 += v[j + 1].x; b1 += v[j + 1].y; b2 += v[j + 1].z;
        }
    }
    if (k < re) {
        int e[8];
#pragma unroll
        for (int j = 0; j < 8; ++j) e[j] = csr_src[(k + j < re) ? (k + j) : (re - 1)];
        float4 v[8];
#pragma unroll
        for (int j = 0; j < 8; ++j) v[j] = z4[e[j]];
#pragma unroll
        for (int j = 0; j < 8; ++j) {
            float m = (k + j < re) ? 1.f : 0.f;
            a0 += m * v[j].x; a1 += m * v[j].y; a2 += m * v[j].z;
        }
    }
    float di = deg_inv[n];
    float4 rn = *(const float4*)&r[4 * (size_t)n];
    out[(size_t)n * 3 + 0] = (a0 + b0) * di + rn.x + b4[0];
    out[(size_t)n * 3 + 1] = (a1 + b1) * di + rn.y + b4[1];
    out[(size_t)n * 3 + 2] = (a2 + b2) * di + rn.z + b4[2];
}

extern "C" void kernel_launch(void* const* d_in, const int* in_sizes, int n_in,
                              void* d_out, int out_size, void* d_ws, size_t ws_size,
                              hipStream_t stream) {
    const float* x   = (const float*)d_in[0];
    const int*   ei  = (const int*)d_in[1];
    const float* W1l = (const float*)d_in[2];
    const float* b1  = (const float*)d_in[3];
    const float* W1r = (const float*)d_in[4];
    const float* W2l = (const float*)d_in[5];
    const float* b2  = (const float*)d_in[6];
    const float* W2r = (const float*)d_in[7];
    const float* W4l = (const float*)d_in[8];
    const float* b4  = (const float*)d_in[9];
    const float* W4r = (const float*)d_in[10];
    float* out = (float*)d_out;

    char* ws = (char*)d_ws;
    size_t off = 0;
    auto alloc = [&](size_t bytes) -> void* {
        void* p = ws + off;
        off = (off + bytes + 255) & ~(size_t)255;
        return p;
    };
    int*   row_start = (int*)alloc(((size_t)NN + 1) * 4);
    int*   csr_src   = (int*)alloc((size_t)EE * 4);
    float* deg_inv   = (float*)alloc((size_t)NN * 4);
    int*   pcur      = (int*)alloc((size_t)NBUCKET * 4);
    unsigned short* xb    = (unsigned short*)alloc((size_t)NN * 64 * 2);  // PADDED rows
    unsigned short* h1    = (unsigned short*)alloc((size_t)NN * 64 * 2);
    unsigned short* wpack = (unsigned short*)alloc((size_t)WPACK_SHORTS * 2);
    float* zbuf = (float*)alloc((size_t)NN * 4 * 4);
    float* rbuf = (float*)alloc((size_t)NN * 4 * 4);
    unsigned int* pairs = (unsigned int*)alloc((size_t)NBUCKET * CAP * 4);   // 8.4 MB

    const int* e_src = ei;
    const int* e_dst = ei + EE;

    hipMemsetAsync(pcur, 0, (size_t)NBUCKET * 4, stream);

    // phase 1: bucket + x->bf16(padded) + weight pack, one dispatch
    k_bucket_cvt<<<BUCKET_BLOCKS + CVT_BLOCKS + PACK_BLOCKS, 256, 0, stream>>>(
        e_src, e_dst, pcur, pairs, x, xb, W1l, W1r, W2l, W2r, W4l, W4r, wpack);
    // phase 2: fused degree + scan + row_start/deg_inv + scatter
    k_build<<<NRANGE, 1024, 0, stream>>>(pairs, pcur, row_start, deg_inv, csr_src);

    // layer 1: 40 -> 64 (fused balanced gather + gemm)
    k_fused<64, true, false, W1OFF><<<NCHUNK16, 128, 0, stream>>>(
        xb, row_start, csr_src, wpack, b1, h1, nullptr, nullptr);
    // layer 2+3a: 64 -> 128 (fused balanced gather + gemm + zr transform)
    k_fused<128, true, true, W2OFF><<<NCHUNK16, 128, 0, stream>>>(
        h1, row_start, csr_src, wpack, b2, nullptr, zbuf, rbuf);
    // layer 3b: out = mean(z) + r + b4
    k_final<<<(NN + 255) / 256, 256, 0, stream>>>(zbuf, rbuf, b4, row_start, csr_src, deg_inv, out);
}

// Round 11
// 192.000 us; speedup vs baseline: 1.4873x; 1.4873x over previous
//
#include <hip/hip_runtime.h>
#include <hip/hip_bf16.h>

// GraphSAGE 3-layer: 40 -> 64 -> 128 -> 3, mean aggregation over fixed edges.
// R24 = revert to R22 (best, 192.9 us). R23's balanced gather halved gather
// throughput (divergent node-boundary loops serialized the load pipeline:
// hbm 2.0 -> 1.0 TB/s despite occupancy 26 -> 43%) and is dropped.
// State of the fused layers (R18-R23 probes): ~43 us each at FETCH ~81 MB
// = ~2.1 TB/s random 128B line fills ~ 85% of the 8-XCD fill wall; the
// 12.8 MB gather table exceeds 4 MiB per-XCD L2, so misses are structural.

static constexpr int NN = 100000;
static constexpr int EE = 1600000;
static constexpr int NRANGE = 256;
static constexpr int RSIZE = (NN + NRANGE - 1) / NRANGE;   // 391
static constexpr int RPAD = 512;                           // pow2 >= RSIZE
static constexpr int NBUCKET = 8 * NRANGE;                 // 2048
static constexpr int CAP = 1024;     // per-bucket capacity (mean ~781, +8.7 sigma)
static constexpr int BCHUNK = 2048;  // edges per block (8 per thread)
static constexpr int BUCKET_BLOCKS = (EE + BCHUNK - 1) / BCHUNK;  // 782
static constexpr int CVT_BLOCKS = (NN * 8 + 255) / 256;           // 3125 (padded rows)
static constexpr int NCHUNK16 = NN / 16;                          // 6250 exact
static constexpr int EIDX = 512;     // staged indices per 16-node chunk (mean 256, +16 sigma)

// packed weight-frag layout (shorts): W1 frags | W2 frags | W4 frags
static constexpr int W1OFF = 0;                 // 4 tiles * 4 ks * 64 lanes * 8
static constexpr int W2OFF = 4 * 4 * 64 * 8;    // 8192
static constexpr int W4OFF = W2OFF + 8 * 4 * 64 * 8;  // 24576
static constexpr int WPACK_SHORTS = W4OFF + 4 * 64 * 8;  // 26624
static constexpr int PACK_ITEMS = 4 * 4 * 64 + 8 * 4 * 64 + 4 * 64;  // 3328
static constexpr int PACK_BLOCKS = (PACK_ITEMS + 255) / 256;         // 13

typedef __attribute__((ext_vector_type(8))) short short8;
typedef __attribute__((ext_vector_type(4))) float f32x4;

__device__ __forceinline__ float bf2f(unsigned short u) {
    union { unsigned int i; float f; } c; c.i = ((unsigned int)u) << 16; return c.f;
}
__device__ __forceinline__ unsigned short f2bf(float f) {
    union { float f; unsigned int i; } c; c.f = f;
    unsigned int x = c.i;
    return (unsigned short)((x + 0x7fffu + ((x >> 16) & 1u)) >> 16);   // RNE
}

// ---------------- phase 1 (fused): bucket edges + x->bf16 convert(padded) + weight pack ----------------
__global__ __launch_bounds__(256) void k_bucket_cvt(const int* __restrict__ src, const int* __restrict__ dst,
                                                    int* __restrict__ pcur, unsigned int* __restrict__ pairs,
                                                    const float* __restrict__ x, unsigned short* __restrict__ xb,
                                                    const float* __restrict__ W1l, const float* __restrict__ W1r,
                                                    const float* __restrict__ W2l, const float* __restrict__ W2r,
                                                    const float* __restrict__ W4l, const float* __restrict__ W4r,
                                                    unsigned short* __restrict__ wpack) {
    __shared__ int cnt[NRANGE];
    __shared__ int base[NRANGE];
    const int tid = threadIdx.x;
    if (blockIdx.x >= BUCKET_BLOCKS + CVT_BLOCKS) {
        // ---- weight-pack branch: frag layout (t*KS+ks)*64+lane -> short8 ----
        int idx = (blockIdx.x - BUCKET_BLOCKS - CVT_BLOCKS) * 256 + tid;
        if (idx < PACK_ITEMS) {
            short8 v;
            if (idx < 1024) {                       // W1: Fin=40, 4 tiles
                int l = idx & 63, ks = (idx >> 6) & 3, t = idx >> 8;
                int o = t * 16 + (l & 15);
                int kbase = ks * 32 + (l >> 4) * 8;
#pragma unroll
                for (int j = 0; j < 8; ++j) {
                    int k = kbase + j; float w;
                    if (k < 64) w = (k < 40) ? W1l[o * 40 + k] : 0.f;
                    else { int k2 = k - 64; w = (k2 < 40) ? W1r[o * 40 + k2] : 0.f; }
                    v[j] = (short)f2bf(w);
                }
                *(short8*)&wpack[W1OFF + idx * 8] = v;
            } else if (idx < 3072) {                // W2: Fin=64, 8 tiles
                int i2 = idx - 1024;
                int l = i2 & 63, ks = (i2 >> 6) & 3, t = i2 >> 8;
                int o = t * 16 + (l & 15);
                int kbase = ks * 32 + (l >> 4) * 8;
#pragma unroll
                for (int j = 0; j < 8; ++j) {
                    int k = kbase + j;
                    float w = (k < 64) ? W2l[o * 64 + k] : W2r[o * 64 + (k - 64)];
                    v[j] = (short)f2bf(w);
                }
                *(short8*)&wpack[W2OFF + i2 * 8] = v;
            } else {                                // W4: [z|r] narrow, K=128
                int i4 = idx - 3072;
                int l = i4 & 63, ks = i4 >> 6;
                int o = l & 15;
                int kbase = ks * 32 + (l >> 4) * 8;
#pragma unroll
                for (int j = 0; j < 8; ++j) {
                    int k = kbase + j;
                    float w = 0.f;
                    if (o < 3) w = W4l[o * 128 + k];
                    else if (o >= 4 && o < 7) w = W4r[(o - 4) * 128 + k];
                    v[j] = (short)f2bf(w);
                }
                *(short8*)&wpack[W4OFF + i4 * 8] = v;
            }
        }
        return;
    }
    if (blockIdx.x >= BUCKET_BLOCKS) {
        // ---- convert branch: fp32 -> bf16, rows PADDED 40 -> 64 shorts ----
        int i = (blockIdx.x - BUCKET_BLOCKS) * 256 + tid;     // 8-short chunk id
        if (i < NN * 8) {
            int node = i >> 3, c = i & 7;
            short8 v = {0, 0, 0, 0, 0, 0, 0, 0};
            if (c < 5) {
                const float4* p = (const float4*)(x + (size_t)node * 40 + c * 8);
                float4 a = p[0], b = p[1];
                v[0] = (short)f2bf(a.x); v[1] = (short)f2bf(a.y); v[2] = (short)f2bf(a.z); v[3] = (short)f2bf(a.w);
                v[4] = (short)f2bf(b.x); v[5] = (short)f2bf(b.y); v[6] = (short)f2bf(b.z); v[7] = (short)f2bf(b.w);
            }
            *(short8*)(xb + (size_t)i * 8) = v;
        }
        return;
    }
    // ---- bucket branch: block-local reservation, packed (s | dloc<<17) ----
    const int part = blockIdx.x & 7;            // this block's XCD tag (round-robin)
    const int e0 = blockIdx.x * BCHUNK;
    cnt[tid] = 0;                               // NRANGE == blockDim == 256
    __syncthreads();
    int r_[8], lp_[8];
    unsigned int p_[8];
#pragma unroll
    for (int j = 0; j < 8; ++j) {
        int e = e0 + j * 256 + tid;
        r_[j] = -1;
        if (e < EE) {
            int d = dst[e];
            int s = src[e];
            int r = d / RSIZE;                  // const-divide -> magic mul
            r_[j] = r;
            p_[j] = (unsigned int)s | ((unsigned int)(d - r * RSIZE) << 17);
            lp_[j] = atomicAdd(&cnt[r], 1);     // fast LDS atomic
        }
    }
    __syncthreads();
    {
        int c = cnt[tid];
        base[tid] = (c > 0) ? atomicAdd(&pcur[(part << 8) | tid], c) : 0;  // 1 global RMW / bucket / block
    }
    __syncthreads();
#pragma unroll
    for (int j = 0; j < 8; ++j) {
        if (r_[j] >= 0) {
            int pos = base[r_[j]] + lp_[j];
            if (pos < CAP) pairs[(size_t)((part << 8) | r_[j]) * CAP + pos] = p_[j];
        }
    }
}

// ---------------- fused CSR build: degree count + scan + row_start/deg_inv + scatter ----------------
__global__ __launch_bounds__(1024) void k_build(const unsigned int* __restrict__ pairs,
                                                const int* __restrict__ pcur,
                                                int* __restrict__ row_start, float* __restrict__ deg_inv,
                                                int* __restrict__ csr_src) {
    __shared__ int ldeg[RPAD];
    __shared__ int lrs[RPAD];
    __shared__ int rtot[NRANGE];
    const int tid = threadIdx.x;
    const int r = blockIdx.x;
    const int lo = r * RSIZE;
    const int nloc = (lo + RSIZE <= NN) ? RSIZE : (NN - lo);
    for (int t = tid; t < RPAD; t += 1024) ldeg[t] = 0;
    __syncthreads();
    // pass 1: degree histogram
    for (int p = 0; p < 8; ++p) {
        int b = (p << 8) | r;
        int len = pcur[b]; if (len > CAP) len = CAP;
        const unsigned int* bp = pairs + (size_t)b * CAP;
        for (int i = tid; i < len; i += 1024)
            atomicAdd(&ldeg[bp[i] >> 17], 1);
    }
    // per-range totals from pcur (independent of ldeg)
    if (tid < NRANGE) {
        int s = 0;
#pragma unroll
        for (int p = 0; p < 8; ++p) {
            int c = pcur[(p << 8) | tid];
            s += (c > CAP) ? CAP : c;
        }
        rtot[tid] = s;
    }
    __syncthreads();
    // inclusive scan of rtot (256 values)
    for (int d = 1; d < NRANGE; d <<= 1) {
        int t = (tid < NRANGE && tid >= d) ? rtot[tid - d] : 0;
        __syncthreads();
        if (tid < NRANGE) rtot[tid] += t;
        __syncthreads();
    }
    const int rbase = (r == 0) ? 0 : rtot[r - 1];
    // inclusive scan of ldeg -> lrs (512 values)
    if (tid < RPAD) lrs[tid] = ldeg[tid];
    __syncthreads();
    for (int d = 1; d < RPAD; d <<= 1) {
        int t = (tid < RPAD && tid >= d) ? lrs[tid - d] : 0;
        __syncthreads();
        if (tid < RPAD) lrs[tid] += t;
        __syncthreads();
    }
    // write row_start / deg_inv; convert lrs to exclusive, reset ldeg to cursors
    int excl = 0, dg = 0;
    if (tid < RPAD) { dg = ldeg[tid]; excl = lrs[tid] - dg; }
    if (tid < nloc) {
        row_start[lo + tid] = rbase + excl;
        deg_inv[lo + tid] = (dg > 0) ? 1.0f / (float)dg : 0.0f;
    }
    if (r == 0 && tid == 0) row_start[NN] = EE;
    __syncthreads();
    if (tid < RPAD) { lrs[tid] = excl; ldeg[tid] = 0; }
    __syncthreads();
    // pass 2: scatter
    for (int p = 0; p < 8; ++p) {
        int b = (p << 8) | r;
        int len = pcur[b]; if (len > CAP) len = CAP;
        const unsigned int* bp = pairs + (size_t)b * CAP;
        for (int i = tid; i < len; i += 1024) {
            unsigned int pk = bp[i];
            int dloc = pk >> 17;
            int lp = atomicAdd(&ldeg[dloc], 1);             // LDS cursor
            csr_src[rbase + lrs[dloc] + lp] = (int)(pk & 0x1FFFFu);
        }
    }
}

// ---------------- fused layer: gather-mean (LDS) + MFMA GEMM [+ zr epilogue] ----------------
// One 16-node chunk per 128-thread block (grid = 6250). All feature rows are
// stride-64 shorts (128B aligned lines). Edge indices staged in LDS; row loads
// 4-deep (<=64 VGPR -> 8 waves/SIMD). B-frags streamed per-tile from wpack.
template<int Fout, bool RELU, bool ZR, int WOFF>
__global__ __launch_bounds__(128, 8) void k_fused(const unsigned short* __restrict__ xin,
                                                  const int* __restrict__ row_start,
                                                  const int* __restrict__ csr_src,
                                                  const float* __restrict__ deg_inv,
                                                  const unsigned short* __restrict__ wpack,
                                                  const float* __restrict__ bias,
                                                  unsigned short* __restrict__ out,
                                                  float* __restrict__ z,
                                                  float* __restrict__ rr_) {
    constexpr int KS = 4;
    constexpr int TILES = Fout / 16;
    constexpr int TPW = TILES / 2;              // tiles per wave (2 waves)
    constexpr int SMEAN = 0;                    // [16][72]
    constexpr int SROOT = 16 * 72;              // [16][72]
    constexpr int SH2 = 2 * 16 * 72;            // [16][136] (ZR only)
    constexpr int SHM = 2 * 16 * 72 + (ZR ? 16 * 136 : 0);
    __shared__ short shm[SHM];
    __shared__ int lidx[EIDX];
    const int tid = threadIdx.x;
    const int lane = tid & 63;
    const int wv = tid >> 6;                    // 0..1
    const int nbase = blockIdx.x * 16;

    float bias_t[TPW];
#pragma unroll
    for (int tt = 0; tt < TPW; ++tt) bias_t[tt] = bias[(wv * TPW + tt) * 16 + (lane & 15)];

    // ---- phase A0: stage this chunk's edge indices into LDS (coalesced) ----
    const int rs_blk = row_start[nbase];
    const int re_blk = row_start[nbase + 16];
    const int nedge = re_blk - rs_blk;
    for (int i = tid; i < nedge && i < EIDX; i += 128) lidx[i] = csr_src[rs_blk + i];
    __syncthreads();

    const int node8 = tid >> 3;                 // 0..15
    const int c = tid & 7;

    // ---- phase A: gather-mean + root staging (rows 4-deep in flight) ----
    {
        const int node = nbase + node8;
        float acc[8] = {0, 0, 0, 0, 0, 0, 0, 0};
        const unsigned short* xq = xin + c * 8;
        const int rs = row_start[node], re = row_start[node + 1];
        int k = rs;
        // full 4-batches
        for (; k + 4 <= re; k += 4) {
            short8 v[4];
#pragma unroll
            for (int j = 0; j < 4; ++j) {
                int off = k + j - rs_blk;
                int s = (off < EIDX) ? lidx[off] : csr_src[k + j];
                v[j] = *(const short8*)(xq + (size_t)s * 64);
            }
#pragma unroll
            for (int j = 0; j < 4; ++j)
#pragma unroll
                for (int t = 0; t < 8; ++t) acc[t] += bf2f((unsigned short)v[j][t]);
        }
        // masked tail batch (loads clamped to re-1, contributions x0/x1)
        if (k < re) {
            short8 v[4];
#pragma unroll
            for (int j = 0; j < 4; ++j) {
                int kk = (k + j < re) ? (k + j) : (re - 1);
                int off = kk - rs_blk;
                int s = (off < EIDX) ? lidx[off] : csr_src[kk];
                v[j] = *(const short8*)(xq + (size_t)s * 64);
            }
#pragma unroll
            for (int j = 0; j < 4; ++j) {
                float m = (k + j < re) ? 1.f : 0.f;
#pragma unroll
                for (int t = 0; t < 8; ++t) acc[t] += m * bf2f((unsigned short)v[j][t]);
            }
        }
        float di = deg_inv[node];
        short8 mv;
#pragma unroll
        for (int t = 0; t < 8; ++t) mv[t] = (short)f2bf(acc[t] * di);
        short8 rv = *(const short8*)(xin + (size_t)node * 64 + c * 8);
        *(short8*)&shm[SMEAN + node8 * 72 + c * 8] = mv;
        *(short8*)&shm[SROOT + node8 * 72 + c * 8] = rv;
    }
    __syncthreads();
    // ---- phase B: MFMA. A-frags from LDS once; B-frags streamed from wpack ----
    short8 af[KS];
#pragma unroll
    for (int ks = 0; ks < KS; ++ks) {
        const int base = (ks < 2) ? SMEAN : SROOT;
        const int g = (ks & 1) * 4 + (lane >> 4);
        af[ks] = *(const short8*)&shm[base + (lane & 15) * 72 + g * 8];
    }
    f32x4 acc2[TPW];
#pragma unroll
    for (int tt = 0; tt < TPW; ++tt) acc2[tt] = (f32x4){0.f, 0.f, 0.f, 0.f};
#pragma unroll
    for (int tt = 0; tt < TPW; ++tt) {
        short8 bt[KS];
#pragma unroll
        for (int ks = 0; ks < KS; ++ks)
            bt[ks] = *(const short8*)&wpack[WOFF + (((wv * TPW + tt) * KS + ks) * 64 + lane) * 8];
#pragma unroll
        for (int ks = 0; ks < KS; ++ks)
            acc2[tt] = __builtin_amdgcn_mfma_f32_16x16x32_bf16(af[ks], bt[ks], acc2[tt], 0, 0, 0);
    }
    if constexpr (!ZR) {
        const int nrow = nbase + (lane >> 4) * 4;
#pragma unroll
        for (int tt = 0; tt < TPW; ++tt) {
            int col = (wv * TPW + tt) * 16 + (lane & 15);
#pragma unroll
            for (int q = 0; q < 4; ++q) {
                float v = acc2[tt][q] + bias_t[tt];
                if (RELU) v = fmaxf(v, 0.f);
                out[(size_t)(nrow + q) * Fout + col] = f2bf(v);
            }
        }
    } else {
        // relu'd h2 tile -> LDS
        const int row0 = (lane >> 4) * 4;
#pragma unroll
        for (int tt = 0; tt < TPW; ++tt) {
            int col = (wv * TPW + tt) * 16 + (lane & 15);
#pragma unroll
            for (int q = 0; q < 4; ++q) {
                float v = acc2[tt][q] + bias_t[tt];
                if (RELU) v = fmaxf(v, 0.f);
                shm[SH2 + (row0 + q) * 136 + col] = (short)f2bf(v);
            }
        }
        __syncthreads();
        if (wv == 0) {
            short8 b4r[4];
#pragma unroll
            for (int ks = 0; ks < 4; ++ks)
                b4r[ks] = *(const short8*)&wpack[W4OFF + (ks * 64 + lane) * 8];
            const int row = lane & 15;
            f32x4 az = (f32x4){0.f, 0.f, 0.f, 0.f};
#pragma unroll
            for (int ks = 0; ks < 4; ++ks) {
                short8 a4 = *(const short8*)&shm[SH2 + row * 136 + (ks * 4 + (lane >> 4)) * 8];
                az = __builtin_amdgcn_mfma_f32_16x16x32_bf16(a4, b4r[ks], az, 0, 0, 0);
            }
            const int col = lane & 15;
            const int nr = nbase + (lane >> 4) * 4;
            if (col < 3) {
#pragma unroll
                for (int q = 0; q < 4; ++q) z[(size_t)(nr + q) * 4 + col] = az[q];
            } else if (col >= 4 && col < 7) {
#pragma unroll
                for (int q = 0; q < 4; ++q) rr_[(size_t)(nr + q) * 4 + col - 4] = az[q];
            }
        }
    }
}

// ---------------- final: out = mean(z)[n] + r[n] + b4 (rows 8-deep) ----------------
__global__ __launch_bounds__(256) void k_final(const float* __restrict__ z, const float* __restrict__ r,
                                               const float* __restrict__ b4,
                                               const int* __restrict__ row_start, const int* __restrict__ csr_src,
                                               const float* __restrict__ deg_inv, float* __restrict__ out) {
    int n = blockIdx.x * 256 + threadIdx.x;
    if (n >= NN) return;
    const int rs = row_start[n], re = row_start[n + 1];
    float a0 = 0, a1 = 0, a2 = 0, b0 = 0, b1 = 0, b2 = 0;
    const float4* z4 = (const float4*)z;
    int k = rs;
    for (; k + 8 <= re; k += 8) {
        int e[8];
#pragma unroll
        for (int j = 0; j < 8; ++j) e[j] = csr_src[k + j];
        float4 v[8];
#pragma unroll
        for (int j = 0; j < 8; ++j) v[j] = z4[e[j]];
#pragma unroll
        for (int j = 0; j < 8; j += 2) {
            a0 += v[j].x; a1 += v[j].y; a2 += v[j].z;
            b0 += v[j + 1].x; b1 += v[j + 1].y; b2 += v[j + 1].z;
        }
    }
    if (k < re) {
        int e[8];
#pragma unroll
        for (int j = 0; j < 8; ++j) e[j] = csr_src[(k + j < re) ? (k + j) : (re - 1)];
        float4 v[8];
#pragma unroll
        for (int j = 0; j < 8; ++j) v[j] = z4[e[j]];
#pragma unroll
        for (int j = 0; j < 8; ++j) {
            float m = (k + j < re) ? 1.f : 0.f;
            a0 += m * v[j].x; a1 += m * v[j].y; a2 += m * v[j].z;
        }
    }
    float di = deg_inv[n];
    float4 rn = *(const float4*)&r[4 * (size_t)n];
    out[(size_t)n * 3 + 0] = (a0 + b0) * di + rn.x + b4[0];
    out[(size_t)n * 3 + 1] = (a1 + b1) * di + rn.y + b4[1];
    out[(size_t)n * 3 + 2] = (a2 + b2) * di + rn.z + b4[2];
}

extern "C" void kernel_launch(void* const* d_in, const int* in_sizes, int n_in,
                              void* d_out, int out_size, void* d_ws, size_t ws_size,
                              hipStream_t stream) {
    const float* x   = (const float*)d_in[0];
    const int*   ei  = (const int*)d_in[1];
    const float* W1l = (const float*)d_in[2];
    const float* b1  = (const float*)d_in[3];
    const float* W1r = (const float*)d_in[4];
    const float* W2l = (const float*)d_in[5];
    const float* b2  = (const float*)d_in[6];
    const float* W2r = (const float*)d_in[7];
    const float* W4l = (const float*)d_in[8];
    const float* b4  = (const float*)d_in[9];
    const float* W4r = (const float*)d_in[10];
    float* out = (float*)d_out;

    char* ws = (char*)d_ws;
    size_t off = 0;
    auto alloc = [&](size_t bytes) -> void* {
        void* p = ws + off;
        off = (off + bytes + 255) & ~(size_t)255;
        return p;
    };
    int*   row_start = (int*)alloc(((size_t)NN + 1) * 4);
    int*   csr_src   = (int*)alloc((size_t)EE * 4);
    float* deg_inv   = (float*)alloc((size_t)NN * 4);
    int*   pcur      = (int*)alloc((size_t)NBUCKET * 4);
    unsigned short* xb    = (unsigned short*)alloc((size_t)NN * 64 * 2);  // PADDED rows
    unsigned short* h1    = (unsigned short*)alloc((size_t)NN * 64 * 2);
    unsigned short* wpack = (unsigned short*)alloc((size_t)WPACK_SHORTS * 2);
    float* zbuf = (float*)alloc((size_t)NN * 4 * 4);
    float* rbuf = (float*)alloc((size_t)NN * 4 * 4);
    unsigned int* pairs = (unsigned int*)alloc((size_t)NBUCKET * CAP * 4);   // 8.4 MB

    const int* e_src = ei;
    const int* e_dst = ei + EE;

    hipMemsetAsync(pcur, 0, (size_t)NBUCKET * 4, stream);

    // phase 1: bucket + x->bf16(padded) + weight pack, one dispatch
    k_bucket_cvt<<<BUCKET_BLOCKS + CVT_BLOCKS + PACK_BLOCKS, 256, 0, stream>>>(
        e_src, e_dst, pcur, pairs, x, xb, W1l, W1r, W2l, W2r, W4l, W4r, wpack);
    // phase 2: fused degree + scan + row_start/deg_inv + scatter
    k_build<<<NRANGE, 1024, 0, stream>>>(pairs, pcur, row_start, deg_inv, csr_src);

    // layer 1: 40 -> 64 (fused gather + gemm)
    k_fused<64, true, false, W1OFF><<<NCHUNK16, 128, 0, stream>>>(
        xb, row_start, csr_src, deg_inv, wpack, b1, h1, nullptr, nullptr);
    // layer 2+3a: 64 -> 128 (fused gather + gemm + zr transform)
    k_fused<128, true, true, W2OFF><<<NCHUNK16, 128, 0, stream>>>(
        h1, row_start, csr_src, deg_inv, wpack, b2, nullptr, zbuf, rbuf);
    // layer 3b: out = mean(z) + r + b4
    k_final<<<(NN + 255) / 256, 256, 0, stream>>>(zbuf, rbuf, b4, row_start, csr_src, deg_inv, out);
}

// Round 12
// 188.140 us; speedup vs baseline: 1.5179x; 1.0205x over previous
//
#include <hip/hip_runtime.h>
#include <hip/hip_bf16.h>

// GraphSAGE 3-layer: 40 -> 64 -> 128 -> 3, mean aggregation over fixed edges.
// R25 (on R24): bucket-branch scatter coalescing — the only unprobed kernel.
// Fused layers (2x43us) are at a structural per-XCD compulsory-fill wall
// (6 probes null; FETCH ~81MB = 8 XCD x table size @ invariant 2.1 TB/s).
//  - Pairs staged in LDS sorted by bucket (block-local 256-scan + LDS
//    scatter), then written out bucket-contiguous: ~8-16 lines per wave
//    store instruction vs 64 before (4-8x store-issue efficiency).
//  - CSR within-row order changes (fp32 edge-sum order only; tolerance-
//    equivalent, prior reorderings kept absmax bit-identical).

static constexpr int NN = 100000;
static constexpr int EE = 1600000;
static constexpr int NRANGE = 256;
static constexpr int RSIZE = (NN + NRANGE - 1) / NRANGE;   // 391
static constexpr int RPAD = 512;                           // pow2 >= RSIZE
static constexpr int NBUCKET = 8 * NRANGE;                 // 2048
static constexpr int CAP = 1024;     // per-bucket capacity (mean ~781, +8.7 sigma)
static constexpr int BCHUNK = 2048;  // edges per block (8 per thread)
static constexpr int BUCKET_BLOCKS = (EE + BCHUNK - 1) / BCHUNK;  // 782
static constexpr int CVT_BLOCKS = (NN * 8 + 255) / 256;           // 3125 (padded rows)
static constexpr int NCHUNK16 = NN / 16;                          // 6250 exact
static constexpr int EIDX = 512;     // staged indices per 16-node chunk (mean 256, +16 sigma)

// packed weight-frag layout (shorts): W1 frags | W2 frags | W4 frags
static constexpr int W1OFF = 0;                 // 4 tiles * 4 ks * 64 lanes * 8
static constexpr int W2OFF = 4 * 4 * 64 * 8;    // 8192
static constexpr int W4OFF = W2OFF + 8 * 4 * 64 * 8;  // 24576
static constexpr int WPACK_SHORTS = W4OFF + 4 * 64 * 8;  // 26624
static constexpr int PACK_ITEMS = 4 * 4 * 64 + 8 * 4 * 64 + 4 * 64;  // 3328
static constexpr int PACK_BLOCKS = (PACK_ITEMS + 255) / 256;         // 13

typedef __attribute__((ext_vector_type(8))) short short8;
typedef __attribute__((ext_vector_type(4))) float f32x4;

__device__ __forceinline__ float bf2f(unsigned short u) {
    union { unsigned int i; float f; } c; c.i = ((unsigned int)u) << 16; return c.f;
}
__device__ __forceinline__ unsigned short f2bf(float f) {
    union { float f; unsigned int i; } c; c.f = f;
    unsigned int x = c.i;
    return (unsigned short)((x + 0x7fffu + ((x >> 16) & 1u)) >> 16);   // RNE
}

// ---------------- phase 1 (fused): bucket edges + x->bf16 convert(padded) + weight pack ----------------
__global__ __launch_bounds__(256) void k_bucket_cvt(const int* __restrict__ src, const int* __restrict__ dst,
                                                    int* __restrict__ pcur, unsigned int* __restrict__ pairs,
                                                    const float* __restrict__ x, unsigned short* __restrict__ xb,
                                                    const float* __restrict__ W1l, const float* __restrict__ W1r,
                                                    const float* __restrict__ W2l, const float* __restrict__ W2r,
                                                    const float* __restrict__ W4l, const float* __restrict__ W4r,
                                                    unsigned short* __restrict__ wpack) {
    __shared__ int cnt[NRANGE];
    __shared__ int sbase[NRANGE];               // scan workspace -> exclusive bases
    __shared__ int base[NRANGE];                // global bases
    __shared__ unsigned int spair[BCHUNK];      // staged pairs, bucket-sorted (8KB)
    __shared__ unsigned char sbkt[BCHUNK];      // bucket id per staged slot (2KB)
    const int tid = threadIdx.x;
    if (blockIdx.x >= BUCKET_BLOCKS + CVT_BLOCKS) {
        // ---- weight-pack branch: frag layout (t*KS+ks)*64+lane -> short8 ----
        int idx = (blockIdx.x - BUCKET_BLOCKS - CVT_BLOCKS) * 256 + tid;
        if (idx < PACK_ITEMS) {
            short8 v;
            if (idx < 1024) {                       // W1: Fin=40, 4 tiles
                int l = idx & 63, ks = (idx >> 6) & 3, t = idx >> 8;
                int o = t * 16 + (l & 15);
                int kbase = ks * 32 + (l >> 4) * 8;
#pragma unroll
                for (int j = 0; j < 8; ++j) {
                    int k = kbase + j; float w;
                    if (k < 64) w = (k < 40) ? W1l[o * 40 + k] : 0.f;
                    else { int k2 = k - 64; w = (k2 < 40) ? W1r[o * 40 + k2] : 0.f; }
                    v[j] = (short)f2bf(w);
                }
                *(short8*)&wpack[W1OFF + idx * 8] = v;
            } else if (idx < 3072) {                // W2: Fin=64, 8 tiles
                int i2 = idx - 1024;
                int l = i2 & 63, ks = (i2 >> 6) & 3, t = i2 >> 8;
                int o = t * 16 + (l & 15);
                int kbase = ks * 32 + (l >> 4) * 8;
#pragma unroll
                for (int j = 0; j < 8; ++j) {
                    int k = kbase + j;
                    float w = (k < 64) ? W2l[o * 64 + k] : W2r[o * 64 + (k - 64)];
                    v[j] = (short)f2bf(w);
                }
                *(short8*)&wpack[W2OFF + i2 * 8] = v;
            } else {                                // W4: [z|r] narrow, K=128
                int i4 = idx - 3072;
                int l = i4 & 63, ks = i4 >> 6;
                int o = l & 15;
                int kbase = ks * 32 + (l >> 4) * 8;
#pragma unroll
                for (int j = 0; j < 8; ++j) {
                    int k = kbase + j;
                    float w = 0.f;
                    if (o < 3) w = W4l[o * 128 + k];
                    else if (o >= 4 && o < 7) w = W4r[(o - 4) * 128 + k];
                    v[j] = (short)f2bf(w);
                }
                *(short8*)&wpack[W4OFF + i4 * 8] = v;
            }
        }
        return;
    }
    if (blockIdx.x >= BUCKET_BLOCKS) {
        // ---- convert branch: fp32 -> bf16, rows PADDED 40 -> 64 shorts ----
        int i = (blockIdx.x - BUCKET_BLOCKS) * 256 + tid;     // 8-short chunk id
        if (i < NN * 8) {
            int node = i >> 3, c = i & 7;
            short8 v = {0, 0, 0, 0, 0, 0, 0, 0};
            if (c < 5) {
                const float4* p = (const float4*)(x + (size_t)node * 40 + c * 8);
                float4 a = p[0], b = p[1];
                v[0] = (short)f2bf(a.x); v[1] = (short)f2bf(a.y); v[2] = (short)f2bf(a.z); v[3] = (short)f2bf(a.w);
                v[4] = (short)f2bf(b.x); v[5] = (short)f2bf(b.y); v[6] = (short)f2bf(b.z); v[7] = (short)f2bf(b.w);
            }
            *(short8*)(xb + (size_t)i * 8) = v;
        }
        return;
    }
    // ---- bucket branch: count -> scan -> LDS-sorted staging -> coalesced write-out ----
    const int part = blockIdx.x & 7;            // this block's XCD tag (round-robin)
    const int e0 = blockIdx.x * BCHUNK;
    cnt[tid] = 0;                               // NRANGE == blockDim == 256
    __syncthreads();
    int r_[8], lp_[8];
    unsigned int p_[8];
#pragma unroll
    for (int j = 0; j < 8; ++j) {
        int e = e0 + j * 256 + tid;
        r_[j] = -1;
        if (e < EE) {
            int d = dst[e];
            int s = src[e];
            int r = d / RSIZE;                  // const-divide -> magic mul
            r_[j] = r;
            p_[j] = (unsigned int)s | ((unsigned int)(d - r * RSIZE) << 17);
            lp_[j] = atomicAdd(&cnt[r], 1);     // fast LDS atomic
        }
    }
    __syncthreads();
    // inclusive scan of cnt -> sbase (Hillis-Steele, 256 wide)
    sbase[tid] = cnt[tid];
    __syncthreads();
    for (int d = 1; d < NRANGE; d <<= 1) {
        int t = (tid >= d) ? sbase[tid - d] : 0;
        __syncthreads();
        sbase[tid] += t;
        __syncthreads();
    }
    // convert to exclusive (own slot only) + global reservation
    {
        int c = cnt[tid];
        sbase[tid] -= c;
        base[tid] = (c > 0) ? atomicAdd(&pcur[(part << 8) | tid], c) : 0;  // 1 global RMW / bucket / block
    }
    __syncthreads();
    // scatter into LDS staging, bucket-sorted
#pragma unroll
    for (int j = 0; j < 8; ++j) {
        if (r_[j] >= 0) {
            int slot = sbase[r_[j]] + lp_[j];
            spair[slot] = p_[j];
            sbkt[slot] = (unsigned char)r_[j];
        }
    }
    __syncthreads();
    // coalesced write-out: consecutive slots within a bucket -> consecutive global positions
    const int total = (e0 + BCHUNK <= EE) ? BCHUNK : (EE - e0);
    for (int i = tid; i < total; i += 256) {
        int b = sbkt[i];
        int pos = base[b] + (i - sbase[b]);
        if (pos < CAP) pairs[(size_t)((part << 8) | b) * CAP + pos] = spair[i];
    }
}

// ---------------- fused CSR build: degree count + scan + row_start/deg_inv + scatter ----------------
__global__ __launch_bounds__(1024) void k_build(const unsigned int* __restrict__ pairs,
                                                const int* __restrict__ pcur,
                                                int* __restrict__ row_start, float* __restrict__ deg_inv,
                                                int* __restrict__ csr_src) {
    __shared__ int ldeg[RPAD];
    __shared__ int lrs[RPAD];
    __shared__ int rtot[NRANGE];
    const int tid = threadIdx.x;
    const int r = blockIdx.x;
    const int lo = r * RSIZE;
    const int nloc = (lo + RSIZE <= NN) ? RSIZE : (NN - lo);
    for (int t = tid; t < RPAD; t += 1024) ldeg[t] = 0;
    __syncthreads();
    // pass 1: degree histogram
    for (int p = 0; p < 8; ++p) {
        int b = (p << 8) | r;
        int len = pcur[b]; if (len > CAP) len = CAP;
        const unsigned int* bp = pairs + (size_t)b * CAP;
        for (int i = tid; i < len; i += 1024)
            atomicAdd(&ldeg[bp[i] >> 17], 1);
    }
    // per-range totals from pcur (independent of ldeg)
    if (tid < NRANGE) {
        int s = 0;
#pragma unroll
        for (int p = 0; p < 8; ++p) {
            int c = pcur[(p << 8) | tid];
            s += (c > CAP) ? CAP : c;
        }
        rtot[tid] = s;
    }
    __syncthreads();
    // inclusive scan of rtot (256 values)
    for (int d = 1; d < NRANGE; d <<= 1) {
        int t = (tid < NRANGE && tid >= d) ? rtot[tid - d] : 0;
        __syncthreads();
        if (tid < NRANGE) rtot[tid] += t;
        __syncthreads();
    }
    const int rbase = (r == 0) ? 0 : rtot[r - 1];
    // inclusive scan of ldeg -> lrs (512 values)
    if (tid < RPAD) lrs[tid] = ldeg[tid];
    __syncthreads();
    for (int d = 1; d < RPAD; d <<= 1) {
        int t = (tid < RPAD && tid >= d) ? lrs[tid - d] : 0;
        __syncthreads();
        if (tid < RPAD) lrs[tid] += t;
        __syncthreads();
    }
    // write row_start / deg_inv; convert lrs to exclusive, reset ldeg to cursors
    int excl = 0, dg = 0;
    if (tid < RPAD) { dg = ldeg[tid]; excl = lrs[tid] - dg; }
    if (tid < nloc) {
        row_start[lo + tid] = rbase + excl;
        deg_inv[lo + tid] = (dg > 0) ? 1.0f / (float)dg : 0.0f;
    }
    if (r == 0 && tid == 0) row_start[NN] = EE;
    __syncthreads();
    if (tid < RPAD) { lrs[tid] = excl; ldeg[tid] = 0; }
    __syncthreads();
    // pass 2: scatter
    for (int p = 0; p < 8; ++p) {
        int b = (p << 8) | r;
        int len = pcur[b]; if (len > CAP) len = CAP;
        const unsigned int* bp = pairs + (size_t)b * CAP;
        for (int i = tid; i < len; i += 1024) {
            unsigned int pk = bp[i];
            int dloc = pk >> 17;
            int lp = atomicAdd(&ldeg[dloc], 1);             // LDS cursor
            csr_src[rbase + lrs[dloc] + lp] = (int)(pk & 0x1FFFFu);
        }
    }
}

// ---------------- fused layer: gather-mean (LDS) + MFMA GEMM [+ zr epilogue] ----------------
// One 16-node chunk per 128-thread block (grid = 6250). All feature rows are
// stride-64 shorts (128B aligned lines). Edge indices staged in LDS; row loads
// 4-deep (<=64 VGPR -> 8 waves/SIMD). B-frags streamed per-tile from wpack.
template<int Fout, bool RELU, bool ZR, int WOFF>
__global__ __launch_bounds__(128, 8) void k_fused(const unsigned short* __restrict__ xin,
                                                  const int* __restrict__ row_start,
                                                  const int* __restrict__ csr_src,
                                                  const float* __restrict__ deg_inv,
                                                  const unsigned short* __restrict__ wpack,
                                                  const float* __restrict__ bias,
                                                  unsigned short* __restrict__ out,
                                                  float* __restrict__ z,
                                                  float* __restrict__ rr_) {
    constexpr int KS = 4;
    constexpr int TILES = Fout / 16;
    constexpr int TPW = TILES / 2;              // tiles per wave (2 waves)
    constexpr int SMEAN = 0;                    // [16][72]
    constexpr int SROOT = 16 * 72;              // [16][72]
    constexpr int SH2 = 2 * 16 * 72;            // [16][136] (ZR only)
    constexpr int SHM = 2 * 16 * 72 + (ZR ? 16 * 136 : 0);
    __shared__ short shm[SHM];
    __shared__ int lidx[EIDX];
    const int tid = threadIdx.x;
    const int lane = tid & 63;
    const int wv = tid >> 6;                    // 0..1
    const int nbase = blockIdx.x * 16;

    float bias_t[TPW];
#pragma unroll
    for (int tt = 0; tt < TPW; ++tt) bias_t[tt] = bias[(wv * TPW + tt) * 16 + (lane & 15)];

    // ---- phase A0: stage this chunk's edge indices into LDS (coalesced) ----
    const int rs_blk = row_start[nbase];
    const int re_blk = row_start[nbase + 16];
    const int nedge = re_blk - rs_blk;
    for (int i = tid; i < nedge && i < EIDX; i += 128) lidx[i] = csr_src[rs_blk + i];
    __syncthreads();

    const int node8 = tid >> 3;                 // 0..15
    const int c = tid & 7;

    // ---- phase A: gather-mean + root staging (rows 4-deep in flight) ----
    {
        const int node = nbase + node8;
        float acc[8] = {0, 0, 0, 0, 0, 0, 0, 0};
        const unsigned short* xq = xin + c * 8;
        const int rs = row_start[node], re = row_start[node + 1];
        int k = rs;
        // full 4-batches
        for (; k + 4 <= re; k += 4) {
            short8 v[4];
#pragma unroll
            for (int j = 0; j < 4; ++j) {
                int off = k + j - rs_blk;
                int s = (off < EIDX) ? lidx[off] : csr_src[k + j];
                v[j] = *(const short8*)(xq + (size_t)s * 64);
            }
#pragma unroll
            for (int j = 0; j < 4; ++j)
#pragma unroll
                for (int t = 0; t < 8; ++t) acc[t] += bf2f((unsigned short)v[j][t]);
        }
        // masked tail batch (loads clamped to re-1, contributions x0/x1)
        if (k < re) {
            short8 v[4];
#pragma unroll
            for (int j = 0; j < 4; ++j) {
                int kk = (k + j < re) ? (k + j) : (re - 1);
                int off = kk - rs_blk;
                int s = (off < EIDX) ? lidx[off] : csr_src[kk];
                v[j] = *(const short8*)(xq + (size_t)s * 64);
            }
#pragma unroll
            for (int j = 0; j < 4; ++j) {
                float m = (k + j < re) ? 1.f : 0.f;
#pragma unroll
                for (int t = 0; t < 8; ++t) acc[t] += m * bf2f((unsigned short)v[j][t]);
            }
        }
        float di = deg_inv[node];
        short8 mv;
#pragma unroll
        for (int t = 0; t < 8; ++t) mv[t] = (short)f2bf(acc[t] * di);
        short8 rv = *(const short8*)(xin + (size_t)node * 64 + c * 8);
        *(short8*)&shm[SMEAN + node8 * 72 + c * 8] = mv;
        *(short8*)&shm[SROOT + node8 * 72 + c * 8] = rv;
    }
    __syncthreads();
    // ---- phase B: MFMA. A-frags from LDS once; B-frags streamed from wpack ----
    short8 af[KS];
#pragma unroll
    for (int ks = 0; ks < KS; ++ks) {
        const int base = (ks < 2) ? SMEAN : SROOT;
        const int g = (ks & 1) * 4 + (lane >> 4);
        af[ks] = *(const short8*)&shm[base + (lane & 15) * 72 + g * 8];
    }
    f32x4 acc2[TPW];
#pragma unroll
    for (int tt = 0; tt < TPW; ++tt) acc2[tt] = (f32x4){0.f, 0.f, 0.f, 0.f};
#pragma unroll
    for (int tt = 0; tt < TPW; ++tt) {
        short8 bt[KS];
#pragma unroll
        for (int ks = 0; ks < KS; ++ks)
            bt[ks] = *(const short8*)&wpack[WOFF + (((wv * TPW + tt) * KS + ks) * 64 + lane) * 8];
#pragma unroll
        for (int ks = 0; ks < KS; ++ks)
            acc2[tt] = __builtin_amdgcn_mfma_f32_16x16x32_bf16(af[ks], bt[ks], acc2[tt], 0, 0, 0);
    }
    if constexpr (!ZR) {
        const int nrow = nbase + (lane >> 4) * 4;
#pragma unroll
        for (int tt = 0; tt < TPW; ++tt) {
            int col = (wv * TPW + tt) * 16 + (lane & 15);
#pragma unroll
            for (int q = 0; q < 4; ++q) {
                float v = acc2[tt][q] + bias_t[tt];
                if (RELU) v = fmaxf(v, 0.f);
                out[(size_t)(nrow + q) * Fout + col] = f2bf(v);
            }
        }
    } else {
        // relu'd h2 tile -> LDS
        const int row0 = (lane >> 4) * 4;
#pragma unroll
        for (int tt = 0; tt < TPW; ++tt) {
            int col = (wv * TPW + tt) * 16 + (lane & 15);
#pragma unroll
            for (int q = 0; q < 4; ++q) {
                float v = acc2[tt][q] + bias_t[tt];
                if (RELU) v = fmaxf(v, 0.f);
                shm[SH2 + (row0 + q) * 136 + col] = (short)f2bf(v);
            }
        }
        __syncthreads();
        if (wv == 0) {
            short8 b4r[4];
#pragma unroll
            for (int ks = 0; ks < 4; ++ks)
                b4r[ks] = *(const short8*)&wpack[W4OFF + (ks * 64 + lane) * 8];
            const int row = lane & 15;
            f32x4 az = (f32x4){0.f, 0.f, 0.f, 0.f};
#pragma unroll
            for (int ks = 0; ks < 4; ++ks) {
                short8 a4 = *(const short8*)&shm[SH2 + row * 136 + (ks * 4 + (lane >> 4)) * 8];
                az = __builtin_amdgcn_mfma_f32_16x16x32_bf16(a4, b4r[ks], az, 0, 0, 0);
            }
            const int col = lane & 15;
            const int nr = nbase + (lane >> 4) * 4;
            if (col < 3) {
#pragma unroll
                for (int q = 0; q < 4; ++q) z[(size_t)(nr + q) * 4 + col] = az[q];
            } else if (col >= 4 && col < 7) {
#pragma unroll
                for (int q = 0; q < 4; ++q) rr_[(size_t)(nr + q) * 4 + col - 4] = az[q];
            }
        }
    }
}

// ---------------- final: out = mean(z)[n] + r[n] + b4 (rows 8-deep) ----------------
__global__ __launch_bounds__(256) void k_final(const float* __restrict__ z, const float* __restrict__ r,
                                               const float* __restrict__ b4,
                                               const int* __restrict__ row_start, const int* __restrict__ csr_src,
                                               const float* __restrict__ deg_inv, float* __restrict__ out) {
    int n = blockIdx.x * 256 + threadIdx.x;
    if (n >= NN) return;
    const int rs = row_start[n], re = row_start[n + 1];
    float a0 = 0, a1 = 0, a2 = 0, b0 = 0, b1 = 0, b2 = 0;
    const float4* z4 = (const float4*)z;
    int k = rs;
    for (; k + 8 <= re; k += 8) {
        int e[8];
#pragma unroll
        for (int j = 0; j < 8; ++j) e[j] = csr_src[k + j];
        float4 v[8];
#pragma unroll
        for (int j = 0; j < 8; ++j) v[j] = z4[e[j]];
#pragma unroll
        for (int j = 0; j < 8; j += 2) {
            a0 += v[j].x; a1 += v[j].y; a2 += v[j].z;
            b0 += v[j + 1].x; b1 += v[j + 1].y; b2 += v[j + 1].z;
        }
    }
    if (k < re) {
        int e[8];
#pragma unroll
        for (int j = 0; j < 8; ++j) e[j] = csr_src[(k + j < re) ? (k + j) : (re - 1)];
        float4 v[8];
#pragma unroll
        for (int j = 0; j < 8; ++j) v[j] = z4[e[j]];
#pragma unroll
        for (int j = 0; j < 8; ++j) {
            float m = (k + j < re) ? 1.f : 0.f;
            a0 += m * v[j].x; a1 += m * v[j].y; a2 += m * v[j].z;
        }
    }
    float di = deg_inv[n];
    float4 rn = *(const float4*)&r[4 * (size_t)n];
    out[(size_t)n * 3 + 0] = (a0 + b0) * di + rn.x + b4[0];
    out[(size_t)n * 3 + 1] = (a1 + b1) * di + rn.y + b4[1];
    out[(size_t)n * 3 + 2] = (a2 + b2) * di + rn.z + b4[2];
}

extern "C" void kernel_launch(void* const* d_in, const int* in_sizes, int n_in,
                              void* d_out, int out_size, void* d_ws, size_t ws_size,
                              hipStream_t stream) {
    const float* x   = (const float*)d_in[0];
    const int*   ei  = (const int*)d_in[1];
    const float* W1l = (const float*)d_in[2];
    const float* b1  = (const float*)d_in[3];
    const float* W1r = (const float*)d_in[4];
    const float* W2l = (const float*)d_in[5];
    const float* b2  = (const float*)d_in[6];
    const float* W2r = (const float*)d_in[7];
    const float* W4l = (const float*)d_in[8];
    const float* b4  = (const float*)d_in[9];
    const float* W4r = (const float*)d_in[10];
    float* out = (float*)d_out;

    char* ws = (char*)d_ws;
    size_t off = 0;
    auto alloc = [&](size_t bytes) -> void* {
        void* p = ws + off;
        off = (off + bytes + 255) & ~(size_t)255;
        return p;
    };
    int*   row_start = (int*)alloc(((size_t)NN + 1) * 4);
    int*   csr_src   = (int*)alloc((size_t)EE * 4);
    float* deg_inv   = (float*)alloc((size_t)NN * 4);
    int*   pcur      = (int*)alloc((size_t)NBUCKET * 4);
    unsigned short* xb    = (unsigned short*)alloc((size_t)NN * 64 * 2);  // PADDED rows
    unsigned short* h1    = (unsigned short*)alloc((size_t)NN * 64 * 2);
    unsigned short* wpack = (unsigned short*)alloc((size_t)WPACK_SHORTS * 2);
    float* zbuf = (float*)alloc((size_t)NN * 4 * 4);
    float* rbuf = (float*)alloc((size_t)NN * 4 * 4);
    unsigned int* pairs = (unsigned int*)alloc((size_t)NBUCKET * CAP * 4);   // 8.4 MB

    const int* e_src = ei;
    const int* e_dst = ei + EE;

    hipMemsetAsync(pcur, 0, (size_t)NBUCKET * 4, stream);

    // phase 1: bucket + x->bf16(padded) + weight pack, one dispatch
    k_bucket_cvt<<<BUCKET_BLOCKS + CVT_BLOCKS + PACK_BLOCKS, 256, 0, stream>>>(
        e_src, e_dst, pcur, pairs, x, xb, W1l, W1r, W2l, W2r, W4l, W4r, wpack);
    // phase 2: fused degree + scan + row_start/deg_inv + scatter
    k_build<<<NRANGE, 1024, 0, stream>>>(pairs, pcur, row_start, deg_inv, csr_src);

    // layer 1: 40 -> 64 (fused gather + gemm)
    k_fused<64, true, false, W1OFF><<<NCHUNK16, 128, 0, stream>>>(
        xb, row_start, csr_src, deg_inv, wpack, b1, h1, nullptr, nullptr);
    // layer 2+3a: 64 -> 128 (fused gather + gemm + zr transform)
    k_fused<128, true, true, W2OFF><<<NCHUNK16, 128, 0, stream>>>(
        h1, row_start, csr_src, deg_inv, wpack, b2, nullptr, zbuf, rbuf);
    // layer 3b: out = mean(z) + r + b4
    k_final<<<(NN + 255) / 256, 256, 0, stream>>>(zbuf, rbuf, b4, row_start, csr_src, deg_inv, out);
}